// Round 3
// baseline (113.631 us; speedup 1.0000x reference)
//
#include <hip/hip_runtime.h>

#define B_ 16
#define R_ 4
#define S_ 4
#define T_ 14
#define F_ 2048
constexpr int P_ = F_ / 2;   // vector-of-2 elements along f

typedef float vf __attribute__((ext_vector_type(2)));

struct cplx { vf re, im; };

__device__ __forceinline__ vf vsp(float s){ vf r; r.x = s; r.y = s; return r; }
__device__ __forceinline__ vf vrcp(vf x){ vf r; r.x = __builtin_amdgcn_rcpf(x.x); r.y = __builtin_amdgcn_rcpf(x.y); return r; }
__device__ __forceinline__ vf vrsq(vf x){ vf r; r.x = __builtin_amdgcn_rsqf(x.x); r.y = __builtin_amdgcn_rsqf(x.y); return r; }

__device__ __forceinline__ cplx cmul(cplx a, cplx b) {        // a*b
    return {a.re*b.re - a.im*b.im, a.re*b.im + a.im*b.re};
}
__device__ __forceinline__ cplx cmulc(cplx a, cplx b) {       // conj(a)*b
    return {a.re*b.re + a.im*b.im, a.re*b.im - a.im*b.re};
}
__device__ __forceinline__ cplx cmulcb(cplx a, cplx b) {      // a*conj(b)
    return {a.re*b.re + a.im*b.im, a.im*b.re - a.re*b.im};
}
__device__ __forceinline__ cplx cadd(cplx a, cplx b){ return {a.re+b.re, a.im+b.im}; }
__device__ __forceinline__ cplx csub(cplx a, cplx b){ return {a.re-b.re, a.im-b.im}; }
__device__ __forceinline__ cplx cscale(cplx a, vf s){ return {a.re*s, a.im*s}; }
__device__ __forceinline__ cplx conjc(cplx a){ return {a.re, -a.im}; }
__device__ __forceinline__ vf cnorm(cplx a){ return a.re*a.re + a.im*a.im; }

__global__ __launch_bounds__(256) void sic_lmmse_kernel(
    const float* __restrict__ y_re_, const float* __restrict__ y_im_,
    const float* __restrict__ h_re_, const float* __restrict__ h_im_,
    const int* __restrict__ mask, const float* __restrict__ nv,
    float* __restrict__ out_)
{
    constexpr int BSTP = B_ * S_ * T_ * P_;   // one output plane, in vf units

    int idx = blockIdx.x * 256 + threadIdx.x; // 896*256 threads exactly
    int fv = idx % P_;
    int bt = idx / P_;
    int t  = bt % T_;
    int b  = bt / T_;

    const vf* y_re = (const vf*)y_re_;
    const vf* y_im = (const vf*)y_im_;
    const vf* h_re = (const vf*)h_re_;
    const vf* h_im = (const vf*)h_im_;
    vf*       out  = (vf*)out_;

    float no  = nv[0];
    vf    vno = vsp(no);

    int2 mi = ((const int2*)mask)[t * P_ + fv];
    vf m; m.x = (float)mi.x; m.y = (float)mi.y;

    // ---- gram lower triangle g[i][j] (i>=j) and z = H^H y ----
    cplx g10, g20, g30, g21, g31, g32;        // strict lower
    vf   g00, g11, g22, g33;                  // real diagonals
    cplx z[4];
    #pragma unroll
    for (int i = 0; i < 4; i++) z[i] = { vsp(0.f), vsp(0.f) };
    g10 = g20 = g30 = g21 = g31 = g32 = { vsp(0.f), vsp(0.f) };
    g00 = g11 = g22 = g33 = vsp(0.f);

    #pragma unroll
    for (int r = 0; r < 4; r++) {
        int ybase = ((b * R_ + r) * T_ + t) * P_ + fv;
        cplx yr = { y_re[ybase], y_im[ybase] };
        cplx hr[4];
        #pragma unroll
        for (int s = 0; s < 4; s++) {
            int hbase = (((b * R_ + r) * S_ + s) * T_ + t) * P_ + fv;
            hr[s] = { h_re[hbase], h_im[hbase] };
        }
        #pragma unroll
        for (int s = 0; s < 4; s++) z[s] = cadd(z[s], cmulc(hr[s], yr));
        g00 = g00 + cnorm(hr[0]);
        g11 = g11 + cnorm(hr[1]);
        g22 = g22 + cnorm(hr[2]);
        g33 = g33 + cnorm(hr[3]);
        g10 = cadd(g10, cmulc(hr[1], hr[0]));
        g20 = cadd(g20, cmulc(hr[2], hr[0]));
        g30 = cadd(g30, cmulc(hr[3], hr[0]));
        g21 = cadd(g21, cmulc(hr[2], hr[1]));
        g31 = cadd(g31, cmulc(hr[3], hr[1]));
        g32 = cadd(g32, cmulc(hr[3], hr[2]));
    }

    // ---- reverse Cholesky: A = U U^H, U upper triangular, A = gram + no*I ----
    // U[j][i] entries for j<i; diagonals kept as reciprocals r_i = 1/U[i][i].
    // A[j][i] (j<i) = conj(g[i][j]).
    vf r3 = vrsq(g33 + vno);
    cplx U03 = cscale(conjc(g30), r3);
    cplx U13 = cscale(conjc(g31), r3);
    cplx U23 = cscale(conjc(g32), r3);

    vf r2 = vrsq(g22 + vno - cnorm(U23));
    cplx U02 = cscale(csub(conjc(g20), cmulcb(U03, U23)), r2);
    cplx U12 = cscale(csub(conjc(g21), cmulcb(U13, U23)), r2);

    vf r1 = vrsq(g11 + vno - cnorm(U12) - cnorm(U13));
    cplx U01 = cscale(csub(csub(conjc(g10), cmulcb(U02, U12)), cmulcb(U03, U13)), r1);

    vf r0 = vrsq(g00 + vno - cnorm(U01) - cnorm(U02) - cnorm(U03));

    // ---- V = U^{-1} (upper). V[i][i] = r_i; strict-upper entries: ----
    cplx V01 = cscale(cscale(U01, r1), -r0);
    cplx V12 = cscale(cscale(U12, r2), -r1);
    cplx V23 = cscale(cscale(U23, r3), -r2);
    cplx V02 = cscale(cadd(cmul(U01, V12), cscale(U02, r2)), -r0);
    cplx V13 = cscale(cadd(cmul(U12, V23), cscale(U13, r3)), -r1);
    cplx V03 = cscale(cadd(cadd(cmul(U01, V13), cmul(U02, V23)), cscale(U03, r3)), -r0);

    // ---- SIC: e_k = r_k^2; xz_k = r_k * (V[k, k:] . zres) ----
    int obase0 = ((b * S_) * T_ + t) * P_ + fv;
    constexpr int OSTRIDE = T_ * P_;          // stride between s-planes

    // k = 0
    {
        cplx ts = cadd(cadd(cscale(z[0], r0), cmul(V01, z[1])),
                       cadd(cmul(V02, z[2]), cmul(V03, z[3])));
        vf e = r0 * r0;
        vf drcp = vrcp(vsp(1.0f) - vno * e);
        cplx xk = cscale(ts, r0 * drcp);
        vf ne = vno * e * drcp;
        out[obase0]            = xk.re * m;
        out[BSTP + obase0]     = xk.im * m;
        out[2*BSTP + obase0]   = ne * m;
        z[0] = csub(z[1], cmul(g10, xk));
        z[1] = csub(z[2], cmul(g20, xk));
        z[2] = csub(z[3], cmul(g30, xk));
    }
    // k = 1
    {
        cplx ts = cadd(cadd(cscale(z[0], r1), cmul(V12, z[1])), cmul(V13, z[2]));
        vf e = r1 * r1;
        vf drcp = vrcp(vsp(1.0f) - vno * e);
        cplx xk = cscale(ts, r1 * drcp);
        vf ne = vno * e * drcp;
        int ob = obase0 + OSTRIDE;
        out[ob]            = xk.re * m;
        out[BSTP + ob]     = xk.im * m;
        out[2*BSTP + ob]   = ne * m;
        z[0] = csub(z[1], cmul(g21, xk));
        z[1] = csub(z[2], cmul(g31, xk));
    }
    // k = 2
    {
        cplx ts = cadd(cscale(z[0], r2), cmul(V23, z[1]));
        vf e = r2 * r2;
        vf drcp = vrcp(vsp(1.0f) - vno * e);
        cplx xk = cscale(ts, r2 * drcp);
        vf ne = vno * e * drcp;
        int ob = obase0 + 2 * OSTRIDE;
        out[ob]            = xk.re * m;
        out[BSTP + ob]     = xk.im * m;
        out[2*BSTP + ob]   = ne * m;
        z[0] = csub(z[1], cmul(g32, xk));
    }
    // k = 3
    {
        cplx ts = cscale(z[0], r3);
        vf e = r3 * r3;
        vf drcp = vrcp(vsp(1.0f) - vno * e);
        cplx xk = cscale(ts, r3 * drcp);
        vf ne = vno * e * drcp;
        int ob = obase0 + 3 * OSTRIDE;
        out[ob]            = xk.re * m;
        out[BSTP + ob]     = xk.im * m;
        out[2*BSTP + ob]   = ne * m;
    }
}

extern "C" void kernel_launch(void* const* d_in, const int* in_sizes, int n_in,
                              void* d_out, int out_size, void* d_ws, size_t ws_size,
                              hipStream_t stream) {
    const float* y_re = (const float*)d_in[0];
    const float* y_im = (const float*)d_in[1];
    const float* h_re = (const float*)d_in[2];
    const float* h_im = (const float*)d_in[3];
    const int*   mask = (const int*)  d_in[4];
    const float* nv   = (const float*)d_in[5];
    float* out = (float*)d_out;

    constexpr int N = B_ * T_ * P_;          // 229,376 = 896 * 256
    int threads = 256;
    int blocks  = N / threads;
    hipLaunchKernelGGL(sic_lmmse_kernel, dim3(blocks), dim3(threads), 0, stream,
                       y_re, y_im, h_re, h_im, mask, nv, out);
}